// Round 3
// baseline (844.101 us; speedup 1.0000x reference)
//
#include <hip/hip_runtime.h>
#include <hip/hip_cooperative_groups.h>
#include <hip/hip_bf16.h>
#include <cstddef>
#include <cstdint>

namespace cg = cooperative_groups;

// ---------------------------------------------------------------------------
//  heatmap  (16, 64, 256, 256)  f32
//  pos_embed(16, 32, 256, 256)  f32
//  feat1    (16, 96, 128, 128)  f32
//  feat2    (16,384,  64,  64)  f32
//  feat3    (16,512,  32,  32)  f32
//  W1 (992,1024) ; W2(1024,512) ; W3(512,256) ; W4(256,224)  + biases
//  out (16, 256, 64) f32 : ch 0..223 = MLP out (transposed), 224..255 = positions
//
//  Round-5: cooperative mega-kernel, DE-RISKED vs round-4:
//   * 512 blocks (needs only 2 blocks/CU; budget >= 4 at 17.4KB LDS + 128 VGPR
//     cap) -- 2x co-residency margin against grid.sync deadlock.
//   * every phase grid-strides (2 planes / 2 tiles per block).
//   * gemm_tile ends with __syncthreads so LDS reduce buffer is reusable.
//  Phases: A argmax+gather (2 planes/blk) + wcast (1688 tiles strided)
//          -> grid.sync -> L1..L4 GEMMs (split-K x4 in-block) w/ grid.sync.
//
//  NOTE: ~480 us of dur_us is harness restore/poison (1 GB ws fill @160 us
//  x3) inside the timed window — fixed overhead we cannot touch.
// ---------------------------------------------------------------------------

typedef __attribute__((ext_vector_type(8))) short bf16x8;   // 8 bf16 = 4 VGPRs
typedef __attribute__((ext_vector_type(4))) float f32x4;

// ---- bilinear gather helper ----------------------------------------------
__device__ __forceinline__ void bilinear_block(const float* __restrict__ fb, int C, int H, int W,
                                               float gx, float gy,
                                               __hip_bfloat16* __restrict__ dst, int tid) {
    const float x = (gx + 1.0f) * 0.5f * (float)(W - 1);
    const float y = (gy + 1.0f) * 0.5f * (float)(H - 1);
    const float x0f = floorf(x), y0f = floorf(y);
    const float wx = x - x0f, wy = y - y0f;
    const int x0 = (int)fminf(fmaxf(x0f,       0.f), (float)(W - 1));
    const int x1 = (int)fminf(fmaxf(x0f + 1.f, 0.f), (float)(W - 1));
    const int y0 = (int)fminf(fmaxf(y0f,       0.f), (float)(H - 1));
    const int y1 = (int)fminf(fmaxf(y0f + 1.f, 0.f), (float)(H - 1));
    const float w00 = (1.f - wx) * (1.f - wy);
    const float w01 = wx * (1.f - wy);
    const float w10 = (1.f - wx) * wy;
    const float w11 = wx * wy;
    const int i00 = y0 * W + x0, i01 = y0 * W + x1;
    const int i10 = y1 * W + x0, i11 = y1 * W + x1;
    const size_t HW = (size_t)H * W;
    for (int c = tid; c < C; c += 256) {
        const float* fc = fb + (size_t)c * HW;
        float v = fc[i00] * w00 + fc[i01] * w01 + fc[i10] * w10 + fc[i11] * w11;
        dst[c] = __float2bfloat16(v);
    }
}

// ---- generic split-K x4 MFMA tile: AR x BR 16x16 fragments per wave -------
// A: [M][K] bf16 row-major. Bt: [N][K] bf16. Y = relu(A@W + b).
// Wave w accumulates k-steps {w, w+4, ...}; partials summed through LDS.
// C/D frag: col = lane&15, row = (lane>>4)*4 + reg   [learn_hip m89/m91]
// Ends with __syncthreads: LDS buffer safe to reuse by the next call.
template<int AR, int BR, bool LAST>
__device__ __forceinline__ void gemm_tile(
    const short* __restrict__ A, const short* __restrict__ Bt,
    const float* __restrict__ bias, void* __restrict__ Yv,
    const int N, const int K, const int m0, const int n0,
    float* __restrict__ red, const int tid) {
    const int w = tid >> 6, lane = tid & 63;
    const int q = lane >> 4, r = lane & 15;

    const short* pa[AR];
    const short* pb[BR];
    pa[0] = A + (size_t)(m0 + r) * K + (q << 3);
    #pragma unroll
    for (int i = 1; i < AR; ++i) pa[i] = pa[i - 1] + (size_t)16 * K;
    pb[0] = Bt + (size_t)(n0 + r) * K + (q << 3);
    #pragma unroll
    for (int j = 1; j < BR; ++j) pb[j] = pb[j - 1] + (size_t)16 * K;

    f32x4 acc[AR][BR];
    #pragma unroll
    for (int i = 0; i < AR; ++i)
        #pragma unroll
        for (int j = 0; j < BR; ++j)
            acc[i][j] = (f32x4){0.f, 0.f, 0.f, 0.f};

    const int nk = K >> 5;
    bf16x8 a[AR], b[BR];
    {
        const int off = w << 5;
        #pragma unroll
        for (int i = 0; i < AR; ++i) a[i] = *(const bf16x8*)(pa[i] + off);
        #pragma unroll
        for (int j = 0; j < BR; ++j) b[j] = *(const bf16x8*)(pb[j] + off);
    }
    for (int ks = w + 4; ks < nk; ks += 4) {
        const int off = ks << 5;
        bf16x8 na[AR], nb[BR];
        #pragma unroll
        for (int i = 0; i < AR; ++i) na[i] = *(const bf16x8*)(pa[i] + off);
        #pragma unroll
        for (int j = 0; j < BR; ++j) nb[j] = *(const bf16x8*)(pb[j] + off);
        #pragma unroll
        for (int i = 0; i < AR; ++i)
            #pragma unroll
            for (int j = 0; j < BR; ++j)
                acc[i][j] = __builtin_amdgcn_mfma_f32_16x16x32_bf16(a[i], b[j], acc[i][j], 0, 0, 0);
        #pragma unroll
        for (int i = 0; i < AR; ++i) a[i] = na[i];
        #pragma unroll
        for (int j = 0; j < BR; ++j) b[j] = nb[j];
    }
    #pragma unroll
    for (int i = 0; i < AR; ++i)
        #pragma unroll
        for (int j = 0; j < BR; ++j)
            acc[i][j] = __builtin_amdgcn_mfma_f32_16x16x32_bf16(a[i], b[j], acc[i][j], 0, 0, 0);

    // partials -> LDS, then 256-thread reduce of the 4 wave copies
    constexpr int RL = AR * BR * 4;          // floats per lane
    constexpr int STRIDE = RL + 1;           // pad: conflict-poor
    float* myrow = red + (size_t)(w * 64 + lane) * STRIDE;
    #pragma unroll
    for (int i = 0; i < AR; ++i)
        #pragma unroll
        for (int j = 0; j < BR; ++j)
            #pragma unroll
            for (int t = 0; t < 4; ++t)
                myrow[(i * BR + j) * 4 + t] = acc[i][j][t];
    __syncthreads();

    #pragma unroll
    for (int jj = 0; jj < AR * BR; ++jj) {
        const int e = tid + (jj << 8);       // 0 .. 256*AR*BR-1
        const int le = e / RL;               // lane of origin (RL is pow2 const)
        const int s  = e - le * RL;
        const int frag = s >> 2, i = s & 3;
        const int ar = frag / BR, br = frag - (frag / BR) * BR;
        float v = red[(0 * 64 + le) * STRIDE + s] + red[(1 * 64 + le) * STRIDE + s]
                + red[(2 * 64 + le) * STRIDE + s] + red[(3 * 64 + le) * STRIDE + s];
        const int qe = le >> 4, re = le & 15;
        const int row = m0 + ar * 16 + (qe << 2) + i;
        const int col = n0 + br * 16 + re;
        v = fmaxf(v + bias[col], 0.f);
        if (LAST) {
            // out[b, n, j]: m = b*64 + j ; stride (16384, 64, 1)
            float* O = (float*)Yv;
            O[(size_t)(row >> 6) * 16384 + (size_t)col * 64 + (row & 63)] = v;
        } else {
            __hip_bfloat16* Y = (__hip_bfloat16*)Yv;
            Y[(size_t)row * N + col] = __float2bfloat16(v);
        }
    }
    __syncthreads();                         // LDS reusable by next call
}

// ---- the single cooperative mega-kernel (512 blocks x 256 threads) --------
__global__ __launch_bounds__(256, 4) void mega_kernel(
    const float* __restrict__ hm, const float* __restrict__ pos_embed,
    const float* __restrict__ feat1, const float* __restrict__ feat2,
    const float* __restrict__ feat3,
    const float* __restrict__ W1, const float* __restrict__ W2,
    const float* __restrict__ W3, const float* __restrict__ W4,
    const float* __restrict__ b1, const float* __restrict__ b2,
    const float* __restrict__ b3, const float* __restrict__ b4,
    short* __restrict__ T1, short* __restrict__ T2,
    short* __restrict__ T3, short* __restrict__ T4,
    short* __restrict__ X0, short* __restrict__ X1,
    short* __restrict__ X2, short* __restrict__ X3,
    float* __restrict__ out) {
    __shared__ float smem[4 * 64 * 17];      // 17408 B: gemm reduce / wcast tile
    const int tid = threadIdx.x;
    const int bid = blockIdx.x;
    cg::grid_group grid = cg::this_grid();

    // ---------------- Phase A: per-plane argmax + gather (2 planes/blk) --
    for (int plane = bid; plane < 1024; plane += 512) {
        const float4* p4 = (const float4*)(hm + (size_t)plane * 65536);
        float best = -3.402823466e38f;
        int bidx = 0;
        for (int i2 = tid; i2 < 16384; i2 += 256) {
            float4 v = p4[i2];
            int base = i2 << 2;
            if (v.x > best) { best = v.x; bidx = base; }
            if (v.y > best) { best = v.y; bidx = base + 1; }
            if (v.z > best) { best = v.z; bidx = base + 2; }
            if (v.w > best) { best = v.w; bidx = base + 3; }
        }
        #pragma unroll
        for (int off = 32; off > 0; off >>= 1) {
            float ov = __shfl_down(best, off);
            int   oi = __shfl_down(bidx, off);
            if (ov > best || (ov == best && oi < bidx)) { best = ov; bidx = oi; }
        }
        float* sval = smem;
        int*   sidx = (int*)(smem + 4);
        if ((tid & 63) == 0) { sval[tid >> 6] = best; sidx[tid >> 6] = bidx; }
        __syncthreads();
        float bv = sval[0]; int bi = sidx[0];
        #pragma unroll
        for (int w2 = 1; w2 < 4; ++w2) {
            float ov = sval[w2]; int oi = sidx[w2];
            if (ov > bv || (ov == bv && oi < bi)) { bv = ov; bi = oi; }
        }
        const int idx = bi;
        __syncthreads();                     // smem safe to rewrite next iter

        const int b = plane >> 6, j = plane & 63;
        const int py = idx >> 8, px = idx & 255;
        const float gx = ((float)px - 127.5f) / 127.5f;
        const float gy = ((float)py - 127.5f) / 127.5f;
        if (tid < 32) {
            float v = pos_embed[((size_t)(b * 32 + tid)) * 65536 + idx];
            out[(size_t)b * 16384 + (size_t)(224 + tid) * 64 + j] = v;
        }
        __hip_bfloat16* xrow = (__hip_bfloat16*)X0 + (size_t)plane * 992;
        bilinear_block(feat1 + (size_t)b *  96 * 128 * 128,  96, 128, 128, gx, gy, xrow,       tid);
        bilinear_block(feat2 + (size_t)b * 384 *  64 *  64, 384,  64,  64, gx, gy, xrow +  96, tid);
        bilinear_block(feat3 + (size_t)b * 512 *  32 *  32, 512,  32,  32, gx, gy, xrow + 480, tid);
    }

    // ---------------- Phase A2: weight transpose/cast (1688 tiles) -------
    for (int t = bid; t < 1688; t += 512) {
        int bb = t;
        const float* W; __hip_bfloat16* T; int K, N;
        if (bb < 992)        { W = W1; T = (__hip_bfloat16*)T1; K = 992;  N = 1024; }
        else if (bb < 1504)  { bb -= 992;  W = W2; T = (__hip_bfloat16*)T2; K = 1024; N = 512; }
        else if (bb < 1632)  { bb -= 1504; W = W3; T = (__hip_bfloat16*)T3; K = 512;  N = 256; }
        else                 { bb -= 1632; W = W4; T = (__hip_bfloat16*)T4; K = 256;  N = 224; }
        const int tilesN = N >> 5;
        const int tk = bb / tilesN, tn = bb - tk * tilesN;
        float (*tile)[33] = (float(*)[33])smem;
        const int col = tid & 31, rowg = tid >> 5;   // rowg 0..7
        #pragma unroll
        for (int i = 0; i < 4; ++i) {
            int k = (tk << 5) + rowg + (i << 3);
            tile[rowg + (i << 3)][col] = W[(size_t)k * N + (tn << 5) + col];
        }
        __syncthreads();
        #pragma unroll
        for (int i = 0; i < 4; ++i) {
            int n = (tn << 5) + rowg + (i << 3);
            T[(size_t)n * K + (tk << 5) + col] = __float2bfloat16(tile[col][rowg + (i << 3)]);
        }
        __syncthreads();                     // before next iteration overwrites
    }

    grid.sync();
    // L1: 1024x992 @ 992x1024 -> X1.  1024 32x32 tiles, 2 per block.
    for (int t = bid; t < 1024; t += 512)
        gemm_tile<2, 2, false>(X0, T1, b1, X1, 1024,  992, (t >> 5) << 5, (t & 31) << 5, smem, tid);
    grid.sync();
    // L2: 1024x1024 @ 1024x512 -> X2.  1024 16x32 tiles, 2 per block.
    for (int t = bid; t < 1024; t += 512)
        gemm_tile<1, 2, false>(X1, T2, b2, X2,  512, 1024, (t >> 4) << 4, (t & 15) << 5, smem, tid);
    grid.sync();
    // L3: 1024x512 @ 512x256 -> X3.  1024 16x16 tiles, 2 per block.
    for (int t = bid; t < 1024; t += 512)
        gemm_tile<1, 1, false>(X2, T3, b3, X3,  256,  512, (t >> 4) << 4, (t & 15) << 4, smem, tid);
    grid.sync();
    // L4: 1024x256 @ 256x224 -> out.  896 16x16 tiles, <=2 per block.
    for (int t = bid; t < 896; t += 512)
        gemm_tile<1, 1, true>(X3, T4, b4, out, 224,  256, (t / 14) << 4, (t % 14) << 4, smem, tid);
}

extern "C" void kernel_launch(void* const* d_in, const int* in_sizes, int n_in,
                              void* d_out, int out_size, void* d_ws, size_t ws_size,
                              hipStream_t stream) {
    (void)in_sizes; (void)n_in; (void)out_size; (void)ws_size;
    const float* heatmap   = (const float*)d_in[0];
    const float* pos_embed = (const float*)d_in[1];
    const float* feat1     = (const float*)d_in[2];
    const float* feat2     = (const float*)d_in[3];
    const float* feat3     = (const float*)d_in[4];
    const float* W1 = (const float*)d_in[5];  const float* b1 = (const float*)d_in[6];
    const float* W2 = (const float*)d_in[7];  const float* b2 = (const float*)d_in[8];
    const float* W3 = (const float*)d_in[9];  const float* b3 = (const float*)d_in[10];
    const float* W4 = (const float*)d_in[11]; const float* b4 = (const float*)d_in[12];
    float* out = (float*)d_out;

    char* ws = (char*)d_ws;
    short* X0 = (short*)(ws + 8192);                  // 1024 x 992  bf16
    short* X1 = X0 + (size_t)1024 * 992;              // 1024 x 1024 bf16
    short* X2 = X1 + (size_t)1024 * 1024;             // 1024 x 512  bf16
    short* X3 = X2 + (size_t)1024 * 512;              // 1024 x 256  bf16
    short* T1 = X3 + (size_t)1024 * 256;              // 1024 x 992  bf16 (W1^T)
    short* T2 = T1 + (size_t)1024 * 992;              // 512  x 1024 bf16 (W2^T)
    short* T3 = T2 + (size_t)512 * 1024;              // 256  x 512  bf16 (W3^T)
    short* T4 = T3 + (size_t)256 * 512;               // 224  x 256  bf16 (W4^T)

    void* args[] = {
        (void*)&heatmap, (void*)&pos_embed,
        (void*)&feat1, (void*)&feat2, (void*)&feat3,
        (void*)&W1, (void*)&W2, (void*)&W3, (void*)&W4,
        (void*)&b1, (void*)&b2, (void*)&b3, (void*)&b4,
        (void*)&T1, (void*)&T2, (void*)&T3, (void*)&T4,
        (void*)&X0, (void*)&X1, (void*)&X2, (void*)&X3,
        (void*)&out };
    hipLaunchCooperativeKernel(reinterpret_cast<void*>(mega_kernel),
                               dim3(512), dim3(256), args, 0, stream);
}